// Round 1
// 420.966 us; speedup vs baseline: 1.2284x; 1.2284x over previous
//
#include <hip/hip_runtime.h>

// ---------------------------------------------------------------------------
// QKGainAttention on MI355X (gfx950), round 8.
// R7 postmortem: attn 168us with ALL pipes idle (Mfma 8.4%, VALU 18%,
// HBM 11%) -> latency-bound: per 64x64 tile each wave issues 32 mfma16 but
// also 32 ds_read_b128 + 24 shfl (ds_bpermute chains) with only 2 waves/SIMD.
// R8: (1) QBLK 64->128 (32 queries/wave) + 32x32x16 MFMA: per-barrier MFMA
// work 2x, LDS reads per FLOP halved twice (16B A-frag feeds 32K FLOP).
// (2) P->P^T transpose via v_cvt_pk_bf16_f32 + v_permlane32_swap (pure VALU,
// off the LDS pipe, no divergent selects). (3) s_setprio(1) around MFMA
// clusters. (4) grid 512 = 2 blocks/CU; strip complement via blockIdx.z so
// same-CU pair (n, n+256) is load-balanced (34 tiles/CU). Staging (dbuf,
// XOR swizzle, global_load_lds w16, one barrier/tile) unchanged from R7.
// ---------------------------------------------------------------------------

#define DEVINL __device__ __forceinline__

typedef unsigned short u16;
typedef __bf16 bf16x8 __attribute__((ext_vector_type(8)));
typedef float  f32x4  __attribute__((ext_vector_type(4)));
typedef float  f32x16 __attribute__((ext_vector_type(16)));
typedef short  short8 __attribute__((ext_vector_type(8)));
typedef u16    u16x4  __attribute__((ext_vector_type(4)));
typedef unsigned uint4x __attribute__((ext_vector_type(4)));

static constexpr int T_  = 2048;
static constexpr int C_  = 2048;
static constexpr int TC3 = 6144;   // 3*C

DEVINL u16 f2bf(float f) {
  union { float f; unsigned u; } v; v.f = f;
  unsigned r = v.u + 0x7FFFu + ((v.u >> 16) & 1u);   // RNE
  return (u16)(r >> 16);
}
DEVINL float bf2f(u16 s) {
  union { unsigned u; float f; } v; v.u = ((unsigned)s) << 16;
  return v.f;
}
DEVINL bf16x8 ld8(const u16* p) {
  return __builtin_bit_cast(bf16x8, *(const short8*)p);
}
DEVINL f32x4 mfma16(bf16x8 a, bf16x8 b, f32x4 c) {
  return __builtin_amdgcn_mfma_f32_16x16x32_bf16(a, b, c, 0, 0, 0);
}
DEVINL f32x16 mfma32(bf16x8 a, bf16x8 b, f32x16 c) {
  return __builtin_amdgcn_mfma_f32_32x32x16_bf16(a, b, c, 0, 0, 0);
}
DEVINL void async_cp16(const u16* gp, u16* lp) {
  __builtin_amdgcn_global_load_lds(
      (const __attribute__((address_space(1))) void*)gp,
      (__attribute__((address_space(3))) void*)lp, 16, 0, 0);
}
DEVINL unsigned cvtpk(float lo, float hi) {
  unsigned r;
  asm("v_cvt_pk_bf16_f32 %0, %1, %2" : "=v"(r) : "v"(lo), "v"(hi));
  return r;
}
// v_permlane32_swap_b32: a <- [a.lanes0-31 | b.lanes0-31],
//                        b <- [a.lanes32-63 | b.lanes32-63]
DEVINL void plswap(unsigned& a, unsigned& b) {
  asm("v_permlane32_swap_b32 %0, %1" : "+v"(a), "+v"(b));
}

// ---------------- dtype casts ----------------
__global__ __launch_bounds__(256) void k_cast_x(const float* __restrict__ in,
                                                u16* __restrict__ out) {
  long i = (long)(blockIdx.x * 256 + threadIdx.x) * 4;
  float4 v = *(const float4*)(in + i);
  u16x4 o; o.x = f2bf(v.x); o.y = f2bf(v.y); o.z = f2bf(v.z); o.w = f2bf(v.w);
  *(u16x4*)(out + i) = o;
}
__global__ __launch_bounds__(256) void k_cast_w(const int* __restrict__ in,
                                                u16* __restrict__ out) {
  long i = (long)(blockIdx.x * 256 + threadIdx.x) * 4;
  int4 v = *(const int4*)(in + i);
  u16x4 o; o.x = f2bf((float)v.x); o.y = f2bf((float)v.y);
  o.z = f2bf((float)v.z); o.w = f2bf((float)v.w);
  *(u16x4*)(out + i) = o;
}

// ---------------- GEMM: C[m,n] = (sum_k A[m,k]*Bt[n,k]) * scale[n] ----------
template<bool OUT_BF16>
__global__ __launch_bounds__(256) void k_gemm_bt(
    const u16* __restrict__ A, const u16* __restrict__ Bt,
    const float* __restrict__ scale, void* __restrict__ Cv,
    int N, long K) {
  __shared__ u16 As[128 * 32];
  __shared__ u16 Bs[128 * 32];
  const int tid  = threadIdx.x;
  const int wave = tid >> 6;
  const int lane = tid & 63;
  const int l15  = lane & 15;
  const int quad = lane >> 4;
  const int wm = (wave & 1) * 64;
  const int wn = (wave >> 1) * 64;
  const long bm = (long)blockIdx.y * 128;
  const long bn = (long)blockIdx.x * 128;

  f32x4 acc[4][4] = {};

  const int srow = lane >> 2;
  const int scol = (lane & 3) * 8;

  for (long k0 = 0; k0 < K; k0 += 32) {
#pragma unroll
    for (int i = 0; i < 2; ++i) {
      const int j = wave * 2 + i;
      const int row = j * 16 + srow;
      async_cp16(A  + (bm + row) * K + k0 + scol, &As[j * 512]);
      async_cp16(Bt + (bn + row) * K + k0 + scol, &Bs[j * 512]);
    }
    __syncthreads();
    bf16x8 af[4], bfr[4];
#pragma unroll
    for (int mi = 0; mi < 4; ++mi)
      af[mi] = ld8(&As[(wm + mi * 16 + l15) * 32 + quad * 8]);
#pragma unroll
    for (int ni = 0; ni < 4; ++ni)
      bfr[ni] = ld8(&Bs[(wn + ni * 16 + l15) * 32 + quad * 8]);
#pragma unroll
    for (int mi = 0; mi < 4; ++mi)
#pragma unroll
      for (int ni = 0; ni < 4; ++ni)
        acc[mi][ni] = mfma16(af[mi], bfr[ni], acc[mi][ni]);
    __syncthreads();
  }
#pragma unroll
  for (int ni = 0; ni < 4; ++ni) {
    const long col = bn + wn + ni * 16 + l15;
    const float sc = scale[col];
#pragma unroll
    for (int mi = 0; mi < 4; ++mi) {
      const long row0 = bm + wm + mi * 16 + quad * 4;
#pragma unroll
      for (int r = 0; r < 4; ++r) {
        float v = acc[mi][ni][r] * sc;
        if constexpr (OUT_BF16) ((u16*)Cv)[(row0 + r) * (long)N + col] = f2bf(v);
        else                    ((float*)Cv)[(row0 + r) * (long)N + col] = v;
      }
    }
  }
}

// ---------------- l2norm(q,k); fold qk_gain^2*log2e/sqrt(HD) into q ---------
__global__ __launch_bounds__(256) void k_norm_qk(u16* __restrict__ qkv,
                                                 const float* __restrict__ qk_gain) {
  const int token = blockIdx.x;
  const int wave = threadIdx.x >> 6, lane = threadIdx.x & 63;
  const float g = qk_gain[0];
  const float qmul = g * g * 1.44269504f * 0.08838834764f;
  u16* rowp = qkv + (long)token * TC3;
#pragma unroll
  for (int s = 0; s < 8; ++s) {
    const int seg = wave * 8 + s;
    const int isK = seg >> 4;
    const int h = seg & 15;
    u16* ptr = rowp + isK * C_ + h * 128 + lane * 2;
    unsigned pv = *(const unsigned*)ptr;
    float a = bf2f((u16)(pv & 0xffffu));
    float bb = bf2f((u16)(pv >> 16));
    float ss = a * a + bb * bb;
#pragma unroll
    for (int m = 1; m <= 32; m <<= 1) ss += __shfl_xor(ss, m);
    float denom = fmaxf(sqrtf(ss), 1e-12f);
    float f = (isK ? 1.0f : qmul) / denom;
    u16 o0 = f2bf(a * f), o1 = f2bf(bb * f);
    *(unsigned*)ptr = (unsigned)o0 | ((unsigned)o1 << 16);
  }
}

// ---------------- V transpose: qkv V block -> Vt_g[bz][h][d][t] -------------
__global__ __launch_bounds__(256) void k_vt(const u16* __restrict__ qkv,
                                            u16* __restrict__ vt) {
  const int t0 = blockIdx.x * 64;
  const int h = blockIdx.y, bz = blockIdx.z;
  const int t = threadIdx.x & 63;
  const int d0 = threadIdx.x >> 6;         // 0..3
  const long tokbase = (long)bz * T_;
  const u16* src = qkv + (tokbase + t0 + t) * (long)TC3 + 2 * C_ + h * 128;
  u16* dst = vt + ((long)(bz * 16 + h) * 128) * (long)T_ + t0 + t;
#pragma unroll
  for (int dd = 0; dd < 32; ++dd) {
    const int d = dd * 4 + d0;
    dst[(long)d * T_] = src[d];
  }
}

// ---------------- flash attention (causal), m=0 softmax, 32x32 MFMA ---------
// QBLK=128 (4 waves x 32 queries), KVBLK=64, dbuf LDS, 1 barrier/tile.
__global__ __launch_bounds__(256, 2) void k_attn(const u16* __restrict__ qkv,
                                                 const u16* __restrict__ vtg,
                                                 u16* __restrict__ y) {
  // Strip complement via z: same-CU pair (n, n+256) differs only in z ->
  // qt sums to 15 -> every CU gets a balanced 34-tile load.
  const int qt = blockIdx.z ? (15 - blockIdx.x) : blockIdx.x;
  const int h  = blockIdx.y;
  const int bz = blockIdx.z;
  const int tid = threadIdx.x, w = tid >> 6, lane = tid & 63;
  const int m31 = lane & 31, hi = lane >> 5;

  __shared__ u16 Ks[2][64 * 128];
  __shared__ u16 Vt[2][128 * 64];

  const long tokbase = (long)bz * T_;
  const int qbase = qt * 128 + w * 32;     // 32 queries per wave
  const u16* vbase = vtg + ((long)(bz * 16 + h) * 128) * (long)T_;
  const u16* kbase = qkv + tokbase * TC3 + C_ + h * 128;

  // Q B-frags (32x32x16: col=lane&31=query, k=d=kc*16+hi*8+i)
  bf16x8 qf[8];
  {
    const u16* qp = qkv + (tokbase + qbase + m31) * (long)TC3 + h * 128 + hi * 8;
#pragma unroll
    for (int kc = 0; kc < 8; ++kc)
      qf[kc] = ld8(qp + kc * 16);
  }

  f32x16 o[4];                             // O^T: d=db*32+crow(reg,hi), q=m31
#pragma unroll
  for (int i = 0; i < 4; ++i)
#pragma unroll
    for (int r = 0; r < 16; ++r) o[i][r] = 0.f;
  f32x4 lacc = {0.f, 0.f, 0.f, 0.f};       // per-lane partial row sums (m==0)

  auto stage = [&](int ktb, int b) {
#pragma unroll
    for (int j = 0; j < 4; ++j) {
      const int t = w * 4 + j;
      const int p = t * 64 + lane;
      const int r  = p >> 4, ck = p & 15;          // K: row r, chunk ck
      async_cp16(kbase + (long)(ktb + r) * TC3 + ((ck ^ (r & 15)) * 8),
                 &Ks[b][t * 512]);
      const int d  = p >> 3, cv = p & 7;           // V: row d, chunk cv
      async_cp16(vbase + (long)d * T_ + ktb + ((cv ^ (d & 7)) * 8),
                 &Vt[b][t * 512]);
    }
  };

  stage(0, 0);
  __syncthreads();                         // drain tile-0 staging
  int b = 0;
  const int ktmax = 2 * qt + 1;

  for (int kt = 0; kt <= ktmax; ++kt) {
    const int ktb = kt * 64;
    // prefetch next tile into the other buffer (drained at the barrier
    // AFTER compute -> latency overlapped with compute)
    if (kt < ktmax) stage(ktb + 64, b ^ 1);

    if (ktb <= qbase + 31) {               // skip fully-masked tiles
      // --- S^T = K.Q^T (32x32x16): C frag key=kb*32+crow, query=m31 ---
      f32x16 sA[2];
      __builtin_amdgcn_s_setprio(1);
#pragma unroll
      for (int kb = 0; kb < 2; ++kb) {
        f32x16 acc;
#pragma unroll
        for (int r = 0; r < 16; ++r) acc[r] = 0.f;
#pragma unroll
        for (int kc = 0; kc < 8; ++kc) {
          bf16x8 kf = ld8(&Ks[b][(kb * 32 + m31) * 128 +
                                 (((2 * kc + hi) ^ (lane & 15)) * 8)]);
          acc = mfma32(kf, qf[kc], acc);
        }
        sA[kb] = acc;
      }
      __builtin_amdgcn_s_setprio(0);

      // --- causal mask (one tile per wave hits this) ---
      if (ktb + 63 > qbase) {
        const int qq = qbase + m31;
#pragma unroll
        for (int kb = 0; kb < 2; ++kb)
#pragma unroll
          for (int r = 0; r < 16; ++r) {
            const int key = ktb + kb * 32 + (r & 3) + 8 * (r >> 2) + 4 * hi;
            if (key > qq) sA[kb][r] = -1e30f;
          }
      }
      // --- m=0 softmax: P = exp2(s), 4-way partial sum chains ---
#pragma unroll
      for (int kb = 0; kb < 2; ++kb)
#pragma unroll
        for (int r = 0; r < 16; ++r) {
          float p = __builtin_amdgcn_exp2f(sA[kb][r]);
          sA[kb][r] = p;
          lacc[r & 3] += p;
        }

      // --- P^T B-frags via cvt_pk + permlane32_swap (pure VALU):
      // frag[ks] keys = 16ks + 8H + 0..7; quads qe=2j, qo=2j+1 of kb=ks>>1:
      // word0=swap(w0e,w0o).x word1=swap(w1e,w1o).x word2=.y word3=.y ---
      bf16x8 pb[4];
#pragma unroll
      for (int ks = 0; ks < 4; ++ks) {
        const int kb = ks >> 1, j = ks & 1;
        unsigned w0a = cvtpk(sA[kb][8 * j + 0], sA[kb][8 * j + 1]);
        unsigned w1a = cvtpk(sA[kb][8 * j + 2], sA[kb][8 * j + 3]);
        unsigned w0b = cvtpk(sA[kb][8 * j + 4], sA[kb][8 * j + 5]);
        unsigned w1b = cvtpk(sA[kb][8 * j + 6], sA[kb][8 * j + 7]);
        plswap(w0a, w0b);                  // w0a=word0, w0b=word2
        plswap(w1a, w1b);                  // w1a=word1, w1b=word3
        uint4x t; t.x = w0a; t.y = w1a; t.z = w0b; t.w = w1b;
        pb[ks] = __builtin_bit_cast(bf16x8, t);
      }

      // --- O^T += V^T.P^T: A=V^T rows d, k=keys ks*16+hi*8+i ---
      __builtin_amdgcn_s_setprio(1);
#pragma unroll
      for (int db = 0; db < 4; ++db)
#pragma unroll
        for (int ks = 0; ks < 4; ++ks) {
          bf16x8 vf = ld8(&Vt[b][(db * 32 + m31) * 64 +
                                 (((2 * ks + hi) ^ (m31 & 7)) * 8)]);
          o[db] = mfma32(vf, pb[ks], o[db]);
        }
      __builtin_amdgcn_s_setprio(0);
    }

    if (kt < ktmax) __syncthreads();       // drains prefetch + guards buffers
    b ^= 1;
  }

  // --- epilogue: l = sum over both lane halves; write O^T ---
  float lrow = lacc[0] + lacc[1] + lacc[2] + lacc[3];
  lrow += __shfl_xor(lrow, 32);
  const float inv_l = 1.0f / lrow;
  u16* yp = y + (tokbase + qbase + m31) * (long)C_ + h * 128 + 4 * hi;
#pragma unroll
  for (int db = 0; db < 4; ++db)
#pragma unroll
    for (int g = 0; g < 4; ++g) {
      u16x4 pk;
#pragma unroll
      for (int r = 0; r < 4; ++r) pk[r] = f2bf(o[db][g * 4 + r] * inv_l);
      *(u16x4*)(yp + db * 32 + g * 8) = pk;
    }
}

// ---------------------------------------------------------------------------
extern "C" void kernel_launch(void* const* d_in, const int* in_sizes, int n_in,
                              void* d_out, int out_size, void* d_ws, size_t ws_size,
                              hipStream_t stream) {
  const float* x    = (const float*)d_in[0];
  const int*   aw   = (const int*)d_in[1];
  const float* asc  = (const float*)d_in[2];
  const int*   pw   = (const int*)d_in[3];
  const float* psc  = (const float*)d_in[4];
  const float* gain = (const float*)d_in[5];

  char* ws = (char*)d_ws;
  u16* xb  = (u16*)(ws);                         // 16.78 MB (reused as Vt_g)
  u16* wab = (u16*)(ws + 16777216UL);
  u16* wpb = (u16*)(ws + 41943040UL);
  u16* qkv = (u16*)(ws + 50331648UL);
  u16* yb  = (u16*)(ws + 100663296UL);
  u16* vtg = xb;                                 // x_bf16 dead after QKV GEMM

  k_cast_x<<<8192, 256, 0, stream>>>(x, xb);
  k_cast_w<<<12288, 256, 0, stream>>>(aw, wab);
  k_cast_w<<<4096, 256, 0, stream>>>(pw, wpb);
  k_gemm_bt<true><<<dim3(48, 32), 256, 0, stream>>>(xb, wab, asc, qkv, TC3, (long)C_);
  k_norm_qk<<<4096, 256, 0, stream>>>(qkv, gain);
  k_vt<<<dim3(32, 16, 2), 256, 0, stream>>>(qkv, vtg);
  k_attn<<<dim3(16, 16, 2), 256, 0, stream>>>(qkv, vtg, yb);
  k_gemm_bt<false><<<dim3(16, 32), 256, 0, stream>>>(yb, wpb, psc, (float*)d_out, C_, (long)C_);
}